// Round 7
// baseline (2138.725 us; speedup 1.0000x reference)
//
#include <hip/hip_runtime.h>
#include <math.h>

#define SS 2048
#define BB 64
#define XDIM 64
#define DXF 128
#define HH 256
#define DHH 128

typedef float v2f __attribute__((ext_vector_type(2)));

// tanh(x) = 1 - 2/(exp(2x)+1); __expf -> v_exp_f32, ~1e-6 abs err, saturates correctly.
__device__ __forceinline__ float ftanh(float x) {
    float e = __expf(2.0f * x);
    return 1.0f - 2.0f / (e + 1.0f);
}

// ---------------------------------------------------------------------------
// K1: u[e,i] = bih[i]+bhh[i] + sum_j tanh(bx[j] + sum_m x[e,m]Wx[m,j]) * Wih[i,j]
// 64 rows/block, 256 threads. Register tiles: 4 cols x 4 rows, float4 LDS reads.
// ---------------------------------------------------------------------------
__global__ __launch_bounds__(256) void k1_featu(
    const float* __restrict__ x, const float* __restrict__ Wx,
    const float* __restrict__ bx, const float* __restrict__ Wih,
    const float* __restrict__ bih, const float* __restrict__ bhh,
    float* __restrict__ u)
{
    __shared__ float xs[64][XDIM];   // 16KB
    __shared__ float fs[64][DXF];    // 32KB
    const int tid = threadIdx.x;
    const size_t row0 = (size_t)blockIdx.x * 64;

    for (int v = tid; v < 64 * XDIM; v += 256) {
        int r = v >> 6, m = v & 63;
        xs[r][m] = x[(row0 + r) * XDIM + m];
    }
    __syncthreads();

    // stage 2: fs = tanh(xs @ Wx + bx). cols: cq+32j; rows: 8ru..8ru+7
    {
        const int cq = tid & 31;
        const int ru = tid >> 5;
        v2f aA[2][4], aB[2][4];
        #pragma unroll
        for (int g = 0; g < 2; ++g)
            #pragma unroll
            for (int i = 0; i < 4; ++i) { aA[g][i] = (v2f)0.f; aB[g][i] = (v2f)0.f; }

        #pragma unroll
        for (int kc = 0; kc < 4; ++kc) {          // K=64, KC=16
            v2f wA[16], wB[16];
            #pragma unroll
            for (int k = 0; k < 16; ++k) {
                const float* wp = Wx + (kc * 16 + k) * DXF + cq;
                wA[k] = (v2f){wp[0],  wp[32]};
                wB[k] = (v2f){wp[64], wp[96]};
            }
            #pragma unroll
            for (int g = 0; g < 2; ++g) {
                const int rb = 8 * ru + 4 * g;
                #pragma unroll
                for (int k4 = 0; k4 < 4; ++k4) {
                    float4 xv[4];
                    #pragma unroll
                    for (int i = 0; i < 4; ++i)
                        xv[i] = *(const float4*)&xs[rb + i][kc * 16 + 4 * k4];
                    #pragma unroll
                    for (int i = 0; i < 4; ++i) {
                        #pragma unroll
                        for (int e = 0; e < 4; ++e) {
                            const float xe = (e == 0) ? xv[i].x : (e == 1) ? xv[i].y
                                           : (e == 2) ? xv[i].z : xv[i].w;
                            const v2f xb = (v2f){xe, xe};
                            aA[g][i] += wA[4 * k4 + e] * xb;
                            aB[g][i] += wB[4 * k4 + e] * xb;
                        }
                    }
                }
            }
        }
        const float b0 = bx[cq], b1 = bx[cq + 32], b2 = bx[cq + 64], b3 = bx[cq + 96];
        #pragma unroll
        for (int g = 0; g < 2; ++g)
            #pragma unroll
            for (int i = 0; i < 4; ++i) {
                const int r = 8 * ru + 4 * g + i;
                fs[r][cq]      = ftanh(aA[g][i].x + b0);
                fs[r][cq + 32] = ftanh(aA[g][i].y + b1);
                fs[r][cq + 64] = ftanh(aB[g][i].x + b2);
                fs[r][cq + 96] = ftanh(aB[g][i].y + b3);
            }
    }
    __syncthreads();

    // stage 3: u = fs @ Wih^T + bih + bhh. cols q4+64j; rows 16rq..16rq+15
    {
        const int q4 = tid & 63;
        const int rq = tid >> 6;
        v2f aA[4][4], aB[4][4];
        #pragma unroll
        for (int g = 0; g < 4; ++g)
            #pragma unroll
            for (int i = 0; i < 4; ++i) { aA[g][i] = (v2f)0.f; aB[g][i] = (v2f)0.f; }

        #pragma unroll
        for (int kc = 0; kc < 8; ++kc) {          // K=128, KC=16
            v2f wA[16], wB[16];
            #pragma unroll
            for (int k4 = 0; k4 < 4; ++k4) {
                const float4 w0 = *(const float4*)(Wih + (size_t)(q4      ) * DXF + kc * 16 + 4 * k4);
                const float4 w1 = *(const float4*)(Wih + (size_t)(q4 +  64) * DXF + kc * 16 + 4 * k4);
                const float4 w2 = *(const float4*)(Wih + (size_t)(q4 + 128) * DXF + kc * 16 + 4 * k4);
                const float4 w3 = *(const float4*)(Wih + (size_t)(q4 + 192) * DXF + kc * 16 + 4 * k4);
                wA[4 * k4 + 0] = (v2f){w0.x, w1.x}; wA[4 * k4 + 1] = (v2f){w0.y, w1.y};
                wA[4 * k4 + 2] = (v2f){w0.z, w1.z}; wA[4 * k4 + 3] = (v2f){w0.w, w1.w};
                wB[4 * k4 + 0] = (v2f){w2.x, w3.x}; wB[4 * k4 + 1] = (v2f){w2.y, w3.y};
                wB[4 * k4 + 2] = (v2f){w2.z, w3.z}; wB[4 * k4 + 3] = (v2f){w2.w, w3.w};
            }
            #pragma unroll
            for (int g = 0; g < 4; ++g) {
                const int rb = 16 * rq + 4 * g;
                #pragma unroll
                for (int k4 = 0; k4 < 4; ++k4) {
                    float4 fv[4];
                    #pragma unroll
                    for (int i = 0; i < 4; ++i)
                        fv[i] = *(const float4*)&fs[rb + i][kc * 16 + 4 * k4];
                    #pragma unroll
                    for (int i = 0; i < 4; ++i) {
                        #pragma unroll
                        for (int e = 0; e < 4; ++e) {
                            const float fe = (e == 0) ? fv[i].x : (e == 1) ? fv[i].y
                                           : (e == 2) ? fv[i].z : fv[i].w;
                            const v2f fb = (v2f){fe, fe};
                            aA[g][i] += wA[4 * k4 + e] * fb;
                            aB[g][i] += wB[4 * k4 + e] * fb;
                        }
                    }
                }
            }
        }
        const float b0 = bih[q4]       + bhh[q4];
        const float b1 = bih[q4 + 64]  + bhh[q4 + 64];
        const float b2 = bih[q4 + 128] + bhh[q4 + 128];
        const float b3 = bih[q4 + 192] + bhh[q4 + 192];
        #pragma unroll
        for (int g = 0; g < 4; ++g)
            #pragma unroll
            for (int i = 0; i < 4; ++i) {
                const size_t row = row0 + 16 * rq + 4 * g + i;
                u[row * HH + q4]       = aA[g][i].x + b0;
                u[row * HH + q4 + 64]  = aA[g][i].y + b1;
                u[row * HH + q4 + 128] = aB[g][i].x + b2;
                u[row * HH + q4 + 192] = aB[g][i].y + b3;
            }
    }
}

// ---------------------------------------------------------------------------
// K2: sequential recurrence, WHOLE t-LOOP IN RAW ASM with hard-coded physical
// registers (v0..v119 clobbered). R1-R6 proved the RA re-streams/spills any
// per-thread weight array no matter the source idiom; inside one asm block it
// cannot touch the allocation, so the 64 Whh floats/thread live in v0..v63
// for all 2048 steps.
//
// 1024 threads/block, 1 block/batch. Thread (rg=tid>>4, c=tid&15) owns rows
// 4rg..4rg+3, k in [16c,16c+16). h-reads: 4x ds_read_b128 with (j+(c>>1))&3
// swizzle -> 16 lane-addresses land 2-per-bank-quad = free (m136). 32
// v_pk_fma_f32; 16-lane DPP prefix reduce (4 interleaved chains, no DPP
// hazards); exec-masked tail (lanes c==15 -> rows +0,+1; c==0 -> rows +2,+3)
// does tanh (v_exp), hist store (pre-update h), u prefetch, ds_write of new h.
// Register map: v0-63 w | v64-79 h | v80-87 acc | v90-93 rd | v94 wr |
// v96-97 hist | v98-99 u | v100-101 hold | v102-103 alpha | v104-105 ucur |
// v106 c | v108-117 temps.
// ---------------------------------------------------------------------------
__global__ __launch_bounds__(1024) void k2_rnn(
    const float* __restrict__ u, const float* __restrict__ Whh,
    const float* __restrict__ sigmas, float* __restrict__ hist)
{
    __shared__ float hbuf[2][HH];
    const int tid = threadIdx.x;
    const int b = blockIdx.x;

    const bool hi = ((tid & 15) == 15);
    const float ax = 1.f / (1.f + __expf(-sigmas[hi ? 0 : 2]));
    const float ay = 1.f / (1.f + __expf(-sigmas[hi ? 1 : 3]));

    const float* ub = u + (size_t)b * HH;
    float* hb = hist + (size_t)b * HH;
    const unsigned ulo = (unsigned)(uintptr_t)ub;
    const unsigned uhi = (unsigned)((uintptr_t)ub >> 32);
    const unsigned hlo = (unsigned)(uintptr_t)hb;
    const unsigned hhi = (unsigned)((uintptr_t)hb >> 32);
    const unsigned wlo = (unsigned)(uintptr_t)Whh;
    const unsigned whi = (unsigned)((uintptr_t)Whh >> 32);
    const unsigned lb  = (unsigned)(uintptr_t)(void*)&hbuf[0][0];  // LDS offset (aperture 4GB-aligned)

    asm volatile(
        // ---------------- prologue ----------------
        "v_and_b32 v106, 15, %[tid]\n\t"            // c
        "v_lshrrev_b32 v107, 4, %[tid]\n\t"         // rg
        "v_lshrrev_b32 v108, 1, v106\n\t"
        "v_and_b32 v108, 3, v108\n\t"               // sw = (c>>1)&3
        "v_lshlrev_b32 v109, 6, v106\n\t"           // 64*c (bytes)
        // rd_j (no lds base yet): 64c + 16*((j+sw)&3)
        "v_lshlrev_b32 v110, 4, v108\n\t"
        "v_add_u32 v90, v109, v110\n\t"
        "v_add_u32 v110, 1, v108\n\t"
        "v_and_b32 v110, 3, v110\n\t"
        "v_lshlrev_b32 v110, 4, v110\n\t"
        "v_add_u32 v91, v109, v110\n\t"
        "v_add_u32 v110, 2, v108\n\t"
        "v_and_b32 v110, 3, v110\n\t"
        "v_lshlrev_b32 v110, 4, v110\n\t"
        "v_add_u32 v92, v109, v110\n\t"
        "v_add_u32 v110, 3, v108\n\t"
        "v_and_b32 v110, 3, v110\n\t"
        "v_lshlrev_b32 v110, 4, v110\n\t"
        "v_add_u32 v93, v109, v110\n\t"
        // weight loads: voff_j = rg*4096 + rd_j ; rows via offset imm 0/1024/2048/3072
        "v_lshlrev_b32 v114, 12, v107\n\t"
        "v_add_u32 v115, v114, v90\n\t"
        "v_mov_b32 v113, %[whi]\n\t"
        "v_add_co_u32 v112, vcc, %[wlo], v115\n\t"
        "v_addc_co_u32 v113, vcc, 0, v113, vcc\n\t"
        "global_load_dwordx4 v[0:3], v[112:113], off\n\t"
        "global_load_dwordx4 v[16:19], v[112:113], off offset:1024\n\t"
        "global_load_dwordx4 v[32:35], v[112:113], off offset:2048\n\t"
        "global_load_dwordx4 v[48:51], v[112:113], off offset:3072\n\t"
        "v_add_u32 v115, v114, v91\n\t"
        "v_mov_b32 v113, %[whi]\n\t"
        "v_add_co_u32 v112, vcc, %[wlo], v115\n\t"
        "v_addc_co_u32 v113, vcc, 0, v113, vcc\n\t"
        "global_load_dwordx4 v[4:7], v[112:113], off\n\t"
        "global_load_dwordx4 v[20:23], v[112:113], off offset:1024\n\t"
        "global_load_dwordx4 v[36:39], v[112:113], off offset:2048\n\t"
        "global_load_dwordx4 v[52:55], v[112:113], off offset:3072\n\t"
        "v_add_u32 v115, v114, v92\n\t"
        "v_mov_b32 v113, %[whi]\n\t"
        "v_add_co_u32 v112, vcc, %[wlo], v115\n\t"
        "v_addc_co_u32 v113, vcc, 0, v113, vcc\n\t"
        "global_load_dwordx4 v[8:11], v[112:113], off\n\t"
        "global_load_dwordx4 v[24:27], v[112:113], off offset:1024\n\t"
        "global_load_dwordx4 v[40:43], v[112:113], off offset:2048\n\t"
        "global_load_dwordx4 v[56:59], v[112:113], off offset:3072\n\t"
        "v_add_u32 v115, v114, v93\n\t"
        "v_mov_b32 v113, %[whi]\n\t"
        "v_add_co_u32 v112, vcc, %[wlo], v115\n\t"
        "v_addc_co_u32 v113, vcc, 0, v113, vcc\n\t"
        "global_load_dwordx4 v[12:15], v[112:113], off\n\t"
        "global_load_dwordx4 v[28:31], v[112:113], off offset:1024\n\t"
        "global_load_dwordx4 v[44:47], v[112:113], off offset:2048\n\t"
        "global_load_dwordx4 v[60:63], v[112:113], off offset:3072\n\t"
        // add LDS base into rd addrs
        "v_add_u32 v90, %[lb], v90\n\t"
        "v_add_u32 v91, %[lb], v91\n\t"
        "v_add_u32 v92, %[lb], v92\n\t"
        "v_add_u32 v93, %[lb], v93\n\t"
        // row0 = 4rg + (c==15 ? 0 : 2)
        "v_add_u32 v110, 1, v106\n\t"
        "v_lshrrev_b32 v110, 3, v110\n\t"
        "v_and_b32 v110, 2, v110\n\t"
        "v_sub_u32 v110, 2, v110\n\t"
        "v_lshlrev_b32 v111, 2, v107\n\t"
        "v_add_u32 v111, v111, v110\n\t"            // row0
        "v_lshlrev_b32 v115, 2, v111\n\t"           // 4*row0
        // wr_addr = lb + 0x400 + 4*row0 (first write -> buf1)
        "v_add_u32 v94, 0x400, v115\n\t"
        "v_add_u32 v94, %[lb], v94\n\t"
        // u addr
        "v_mov_b32 v99, %[uhi]\n\t"
        "v_add_co_u32 v98, vcc, %[ulo], v115\n\t"
        "v_addc_co_u32 v99, vcc, 0, v99, vcc\n\t"
        // hist addr
        "v_mov_b32 v97, %[hhi]\n\t"
        "v_add_co_u32 v96, vcc, %[hlo], v115\n\t"
        "v_addc_co_u32 v97, vcc, 0, v97, vcc\n\t"
        // first u
        "global_load_dwordx2 v[104:105], v[98:99], off\n\t"
        // zero hbuf[0] (each thread zeroes its 4 rows; 16x same-data redundancy)
        "v_lshlrev_b32 v116, 4, v107\n\t"
        "v_add_u32 v116, %[lb], v116\n\t"
        "v_mov_b32 v118, 0\n\t"
        "v_mov_b32 v119, 0\n\t"
        "ds_write_b64 v116, v[118:119]\n\t"
        "ds_write_b64 v116, v[118:119] offset:8\n\t"
        // hold = 0, alpha
        "v_mov_b32 v100, 0\n\t"
        "v_mov_b32 v101, 0\n\t"
        "v_mov_b32 v102, %[ax]\n\t"
        "v_mov_b32 v103, %[ay]\n\t"
        "s_mov_b32 s20, 0x80018001\n\t"
        "s_mov_b32 s21, 0x80018001\n\t"
        "s_mov_b32 s24, 0x4038aa3b\n\t"             // 2*log2(e)
        "s_mov_b32 s25, 0x800\n\t"                  // 2048 steps
        "s_waitcnt vmcnt(0) lgkmcnt(0)\n\t"
        "s_barrier\n\t"
        // ---------------- main loop ----------------
        "Lk2loop_%=:\n\t"
        "ds_read_b128 v[64:67], v90\n\t"
        "ds_read_b128 v[68:71], v91\n\t"
        "ds_read_b128 v[72:75], v92\n\t"
        "ds_read_b128 v[76:79], v93\n\t"
        "s_waitcnt lgkmcnt(0)\n\t"
        "v_pk_mul_f32 v[80:81], v[0:1], v[64:65]\n\t"
        "v_pk_mul_f32 v[82:83], v[16:17], v[64:65]\n\t"
        "v_pk_mul_f32 v[84:85], v[32:33], v[64:65]\n\t"
        "v_pk_mul_f32 v[86:87], v[48:49], v[64:65]\n\t"
        "v_pk_fma_f32 v[80:81], v[2:3], v[66:67], v[80:81]\n\t"
        "v_pk_fma_f32 v[82:83], v[18:19], v[66:67], v[82:83]\n\t"
        "v_pk_fma_f32 v[84:85], v[34:35], v[66:67], v[84:85]\n\t"
        "v_pk_fma_f32 v[86:87], v[50:51], v[66:67], v[86:87]\n\t"
        "v_pk_fma_f32 v[80:81], v[4:5], v[68:69], v[80:81]\n\t"
        "v_pk_fma_f32 v[82:83], v[20:21], v[68:69], v[82:83]\n\t"
        "v_pk_fma_f32 v[84:85], v[36:37], v[68:69], v[84:85]\n\t"
        "v_pk_fma_f32 v[86:87], v[52:53], v[68:69], v[86:87]\n\t"
        "v_pk_fma_f32 v[80:81], v[6:7], v[70:71], v[80:81]\n\t"
        "v_pk_fma_f32 v[82:83], v[22:23], v[70:71], v[82:83]\n\t"
        "v_pk_fma_f32 v[84:85], v[38:39], v[70:71], v[84:85]\n\t"
        "v_pk_fma_f32 v[86:87], v[54:55], v[70:71], v[86:87]\n\t"
        "v_pk_fma_f32 v[80:81], v[8:9], v[72:73], v[80:81]\n\t"
        "v_pk_fma_f32 v[82:83], v[24:25], v[72:73], v[82:83]\n\t"
        "v_pk_fma_f32 v[84:85], v[40:41], v[72:73], v[84:85]\n\t"
        "v_pk_fma_f32 v[86:87], v[56:57], v[72:73], v[86:87]\n\t"
        "v_pk_fma_f32 v[80:81], v[10:11], v[74:75], v[80:81]\n\t"
        "v_pk_fma_f32 v[82:83], v[26:27], v[74:75], v[82:83]\n\t"
        "v_pk_fma_f32 v[84:85], v[42:43], v[74:75], v[84:85]\n\t"
        "v_pk_fma_f32 v[86:87], v[58:59], v[74:75], v[86:87]\n\t"
        "v_pk_fma_f32 v[80:81], v[12:13], v[76:77], v[80:81]\n\t"
        "v_pk_fma_f32 v[82:83], v[28:29], v[76:77], v[82:83]\n\t"
        "v_pk_fma_f32 v[84:85], v[44:45], v[76:77], v[84:85]\n\t"
        "v_pk_fma_f32 v[86:87], v[60:61], v[76:77], v[86:87]\n\t"
        "v_pk_fma_f32 v[80:81], v[14:15], v[78:79], v[80:81]\n\t"
        "v_pk_fma_f32 v[82:83], v[30:31], v[78:79], v[82:83]\n\t"
        "v_pk_fma_f32 v[84:85], v[46:47], v[78:79], v[84:85]\n\t"
        "v_pk_fma_f32 v[86:87], v[62:63], v[78:79], v[86:87]\n\t"
        // horizontal
        "v_add_f32 v108, v80, v81\n\t"
        "v_add_f32 v109, v82, v83\n\t"
        "v_add_f32 v110, v84, v85\n\t"
        "v_add_f32 v111, v86, v87\n\t"
        // DPP prefix reduce: rows0/1 -> lane15 (shr), rows2/3 -> lane0 (shl)
        "v_add_f32 v108, v108, v108 row_shr:1 bound_ctrl:0\n\t"
        "v_add_f32 v109, v109, v109 row_shr:1 bound_ctrl:0\n\t"
        "v_add_f32 v110, v110, v110 row_shl:1 bound_ctrl:0\n\t"
        "v_add_f32 v111, v111, v111 row_shl:1 bound_ctrl:0\n\t"
        "v_add_f32 v108, v108, v108 row_shr:2 bound_ctrl:0\n\t"
        "v_add_f32 v109, v109, v109 row_shr:2 bound_ctrl:0\n\t"
        "v_add_f32 v110, v110, v110 row_shl:2 bound_ctrl:0\n\t"
        "v_add_f32 v111, v111, v111 row_shl:2 bound_ctrl:0\n\t"
        "v_add_f32 v108, v108, v108 row_shr:4 bound_ctrl:0\n\t"
        "v_add_f32 v109, v109, v109 row_shr:4 bound_ctrl:0\n\t"
        "v_add_f32 v110, v110, v110 row_shl:4 bound_ctrl:0\n\t"
        "v_add_f32 v111, v111, v111 row_shl:4 bound_ctrl:0\n\t"
        "v_add_f32 v108, v108, v108 row_shr:8 bound_ctrl:0\n\t"
        "v_add_f32 v109, v109, v109 row_shr:8 bound_ctrl:0\n\t"
        "v_add_f32 v110, v110, v110 row_shl:8 bound_ctrl:0\n\t"
        "v_add_f32 v111, v111, v111 row_shl:8 bound_ctrl:0\n\t"
        // select my pair
        "v_cmp_eq_u32 vcc, 15, v106\n\t"
        "v_cndmask_b32 v112, v110, v108, vcc\n\t"
        "v_cndmask_b32 v113, v111, v109, vcc\n\t"
        // masked tail: lanes 0 and 15 of each 16
        "s_and_saveexec_b64 s[22:23], s[20:21]\n\t"
        "s_waitcnt vmcnt(0)\n\t"
        "v_add_f32 v112, v112, v104\n\t"
        "v_add_f32 v113, v113, v105\n\t"
        "v_mul_f32 v114, s24, v112\n\t"
        "v_mul_f32 v115, s24, v113\n\t"
        "v_exp_f32 v114, v114\n\t"
        "v_exp_f32 v115, v115\n\t"
        "v_add_f32 v114, 1.0, v114\n\t"
        "v_add_f32 v115, 1.0, v115\n\t"
        "v_rcp_f32 v114, v114\n\t"
        "v_rcp_f32 v115, v115\n\t"
        "v_fma_f32 v114, -2.0, v114, 1.0\n\t"       // tanh(sv)
        "v_fma_f32 v115, -2.0, v115, 1.0\n\t"
        // store pre-update h (copy first: VMEM may read data regs late)
        "v_mov_b32 v116, v100\n\t"
        "v_mov_b32 v117, v101\n\t"
        "global_store_dwordx2 v[96:97], v[116:117], off\n\t"
        // hold += alpha*(tanh - hold)
        "v_sub_f32 v114, v114, v100\n\t"
        "v_sub_f32 v115, v115, v101\n\t"
        "v_fmac_f32 v100, v102, v114\n\t"
        "v_fmac_f32 v101, v103, v115\n\t"
        "ds_write_b64 v94, v[100:101]\n\t"
        // u prefetch (t+1) and addr increments
        "v_add_co_u32 v98, vcc, 0x10000, v98\n\t"
        "v_addc_co_u32 v99, vcc, 0, v99, vcc\n\t"
        "global_load_dwordx2 v[104:105], v[98:99], off\n\t"
        "v_add_co_u32 v96, vcc, 0x10000, v96\n\t"
        "v_addc_co_u32 v97, vcc, 0, v97, vcc\n\t"
        "s_mov_b64 exec, s[22:23]\n\t"
        // toggle double buffer
        "v_xor_b32 v90, 0x400, v90\n\t"
        "v_xor_b32 v91, 0x400, v91\n\t"
        "v_xor_b32 v92, 0x400, v92\n\t"
        "v_xor_b32 v93, 0x400, v93\n\t"
        "v_xor_b32 v94, 0x400, v94\n\t"
        // barrier + loop
        "s_waitcnt lgkmcnt(0)\n\t"
        "s_barrier\n\t"
        "s_sub_u32 s25, s25, 1\n\t"
        "s_cmp_lg_u32 s25, 0\n\t"
        "s_cbranch_scc1 Lk2loop_%=\n\t"
        :
        : [tid]"v"(tid), [ax]"v"(ax), [ay]"v"(ay), [lb]"v"(lb),
          [ulo]"s"(ulo), [uhi]"s"(uhi), [hlo]"s"(hlo), [hhi]"s"(hhi),
          [wlo]"s"(wlo), [whi]"s"(whi)
        : "memory", "vcc", "scc", "s20", "s21", "s22", "s23", "s24", "s25",
          "v0","v1","v2","v3","v4","v5","v6","v7","v8","v9",
          "v10","v11","v12","v13","v14","v15","v16","v17","v18","v19",
          "v20","v21","v22","v23","v24","v25","v26","v27","v28","v29",
          "v30","v31","v32","v33","v34","v35","v36","v37","v38","v39",
          "v40","v41","v42","v43","v44","v45","v46","v47","v48","v49",
          "v50","v51","v52","v53","v54","v55","v56","v57","v58","v59",
          "v60","v61","v62","v63","v64","v65","v66","v67","v68","v69",
          "v70","v71","v72","v73","v74","v75","v76","v77","v78","v79",
          "v80","v81","v82","v83","v84","v85","v86","v87","v88","v89",
          "v90","v91","v92","v93","v94","v95","v96","v97","v98","v99",
          "v100","v101","v102","v103","v104","v105","v106","v107","v108","v109",
          "v110","v111","v112","v113","v114","v115","v116","v117","v118","v119"
    );
}

// ---------------------------------------------------------------------------
// K3: y[e,o] = bout[o] + sum_k tanh(bhx[k] + sum_i hist[e,i]Whx[i,k]) * Wout[k,o]
// 32 rows/block, 256 threads. Same register-tiling scheme.
// ---------------------------------------------------------------------------
__global__ __launch_bounds__(256) void k3_y(
    const float* __restrict__ hist, const float* __restrict__ Whx,
    const float* __restrict__ bhx, const float* __restrict__ Wout,
    const float* __restrict__ bout, float* __restrict__ y)
{
    __shared__ float hs[32][HH];    // 32KB
    __shared__ float gs[32][DHH];   // 16KB
    const int tid = threadIdx.x;
    const size_t row0 = (size_t)blockIdx.x * 32;

    for (int v = tid; v < 32 * HH; v += 256) {
        int r = v >> 8, i = v & 255;
        hs[r][i] = hist[(row0 + r) * HH + i];
    }
    __syncthreads();

    // stage A: gs = tanh(hs @ Whx + bhx). cols aq+32j; rows 4ru..4ru+3. K=256
    {
        const int aq = tid & 31;
        const int ru = tid >> 5;
        v2f aA[4], aB[4];
        #pragma unroll
        for (int i = 0; i < 4; ++i) { aA[i] = (v2f)0.f; aB[i] = (v2f)0.f; }

        #pragma unroll
        for (int kc = 0; kc < 16; ++kc) {   // KC=16
            v2f wA[16], wB[16];
            #pragma unroll
            for (int k = 0; k < 16; ++k) {
                const float* wp = Whx + (size_t)(kc * 16 + k) * DHH + aq;
                wA[k] = (v2f){wp[0],  wp[32]};
                wB[k] = (v2f){wp[64], wp[96]};
            }
            #pragma unroll
            for (int k4 = 0; k4 < 4; ++k4) {
                float4 hv[4];
                #pragma unroll
                for (int i = 0; i < 4; ++i)
                    hv[i] = *(const float4*)&hs[4 * ru + i][kc * 16 + 4 * k4];
                #pragma unroll
                for (int i = 0; i < 4; ++i) {
                    #pragma unroll
                    for (int e = 0; e < 4; ++e) {
                        const float he = (e == 0) ? hv[i].x : (e == 1) ? hv[i].y
                                       : (e == 2) ? hv[i].z : hv[i].w;
                        const v2f hb = (v2f){he, he};
                        aA[i] += wA[4 * k4 + e] * hb;
                        aB[i] += wB[4 * k4 + e] * hb;
                    }
                }
            }
        }
        const float b0 = bhx[aq], b1 = bhx[aq + 32], b2 = bhx[aq + 64], b3 = bhx[aq + 96];
        #pragma unroll
        for (int i = 0; i < 4; ++i) {
            const int r = 4 * ru + i;
            gs[r][aq]      = ftanh(aA[i].x + b0);
            gs[r][aq + 32] = ftanh(aA[i].y + b1);
            gs[r][aq + 64] = ftanh(aB[i].x + b2);
            gs[r][aq + 96] = ftanh(aB[i].y + b3);
        }
    }
    __syncthreads();

    // stage B: y = gs @ Wout + bout. cols o2, o2+32; rows 4ru..4ru+3. K=128
    {
        const int o2 = tid & 31;
        const int ru = tid >> 5;
        v2f acc[4];
        #pragma unroll
        for (int i = 0; i < 4; ++i) acc[i] = (v2f)0.f;

        #pragma unroll
        for (int kc = 0; kc < 2; ++kc) {    // KC=64
            v2f w[64];
            #pragma unroll
            for (int k = 0; k < 64; ++k) {
                const float* wp = Wout + (size_t)(kc * 64 + k) * XDIM + o2;
                w[k] = (v2f){wp[0], wp[32]};
            }
            #pragma unroll
            for (int k4 = 0; k4 < 16; ++k4) {
                float4 gv[4];
                #pragma unroll
                for (int i = 0; i < 4; ++i)
                    gv[i] = *(const float4*)&gs[4 * ru + i][kc * 64 + 4 * k4];
                #pragma unroll
                for (int i = 0; i < 4; ++i) {
                    #pragma unroll
                    for (int e = 0; e < 4; ++e) {
                        const float ge = (e == 0) ? gv[i].x : (e == 1) ? gv[i].y
                                       : (e == 2) ? gv[i].z : gv[i].w;
                        acc[i] += w[4 * k4 + e] * (v2f){ge, ge};
                    }
                }
            }
        }
        const float b0 = bout[o2], b1 = bout[o2 + 32];
        #pragma unroll
        for (int i = 0; i < 4; ++i) {
            const size_t row = row0 + 4 * ru + i;
            y[row * XDIM + o2]      = acc[i].x + b0;
            y[row * XDIM + o2 + 32] = acc[i].y + b1;
        }
    }
}

extern "C" void kernel_launch(void* const* d_in, const int* in_sizes, int n_in,
                              void* d_out, int out_size, void* d_ws, size_t ws_size,
                              hipStream_t stream) {
    const float* x      = (const float*)d_in[0];
    const float* Wx     = (const float*)d_in[1];
    const float* bx     = (const float*)d_in[2];
    const float* Wih    = (const float*)d_in[3];
    const float* bih    = (const float*)d_in[4];
    const float* Whh    = (const float*)d_in[5];
    const float* bhh    = (const float*)d_in[6];
    const float* Whx    = (const float*)d_in[7];
    const float* bhx    = (const float*)d_in[8];
    const float* Wout   = (const float*)d_in[9];
    const float* bout   = (const float*)d_in[10];
    const float* sigmas = (const float*)d_in[11];
    float* y = (float*)d_out;

    float* u    = (float*)d_ws;                   // S*B*H floats = 128 MB
    float* hist = u + (size_t)SS * BB * HH;       // S*B*H floats = 128 MB

    k1_featu<<<(SS * BB) / 64, 256, 0, stream>>>(x, Wx, bx, Wih, bih, bhh, u);
    k2_rnn<<<BB, 1024, 0, stream>>>(u, Whh, sigmas, hist);
    k3_y<<<(SS * BB) / 32, 256, 0, stream>>>(hist, Whx, bhx, Wout, bout, y);
}